// Round 1
// baseline (4531.771 us; speedup 1.0000x reference)
//
#include <hip/hip_runtime.h>
#include <hip/hip_bf16.h>
#include <math.h>

#define NW 1024
#define TC 16
#define EC 128
#define EW 300
#define HID 512
#define H2 256
#define GATES 1024
#define KC (EC + H2)   // 384
#define KW (EW + HID)  // 812
#define NPOS 48
#define NNER 16

__device__ __forceinline__ float sigf(float x) { return 1.f / (1.f + expf(-x)); }

// ---------------- char LSTM gate GEMM: z[d][n][g] = x_t[n]·Wih[g] + h[n]·Whh[g] ----------------
__global__ __launch_bounds__(256)
void char_gate_gemm(int s,
    const float* __restrict__ char_emb, const int* __restrict__ char_seq,
    const float* __restrict__ Wih_f, const float* __restrict__ Whh_f,
    const float* __restrict__ Wih_b, const float* __restrict__ Whh_b,
    const float* __restrict__ hbuf,   // [par][dir][NW][H2]
    float* __restrict__ zbuf)         // [dir][NW][GATES]
{
    const int d = blockIdx.z;
    const float* Wih = d ? Wih_b : Wih_f;
    const float* Whh = d ? Whh_b : Whh_f;
    const int t_time = d ? (TC - 1 - s) : s;
    const float* hprev = hbuf + (size_t)((s & 1) * 2 + d) * NW * H2;

    __shared__ float As[16][65];
    __shared__ float Bs[16][65];
    const int tid = threadIdx.x;
    const int tx = tid & 15, ty = tid >> 4;
    const int row0 = blockIdx.x * 64;
    const int col0 = blockIdx.y * 64;
    float acc[4][4] = {};
    for (int kb = 0; kb < KC; kb += 16) {
        #pragma unroll
        for (int q = 0; q < 4; ++q) {
            int idx = tid + q * 256;
            int mm = idx >> 4, kk = idx & 15;
            int k = kb + kk;
            int n = row0 + mm;
            float av;
            if (k < EC) {
                int ci = char_seq[n * TC + t_time];
                av = char_emb[(size_t)ci * EC + k];
            } else {
                av = (s == 0) ? 0.f : hprev[(size_t)n * H2 + (k - EC)];
            }
            As[kk][mm] = av;
            int g = col0 + mm;
            Bs[kk][mm] = (k < EC) ? Wih[(size_t)g * EC + k] : Whh[(size_t)g * H2 + (k - EC)];
        }
        __syncthreads();
        #pragma unroll
        for (int kk = 0; kk < 16; ++kk) {
            float a[4], b[4];
            #pragma unroll
            for (int i = 0; i < 4; ++i) a[i] = As[kk][ty * 4 + i];
            #pragma unroll
            for (int j = 0; j < 4; ++j) b[j] = Bs[kk][tx * 4 + j];
            #pragma unroll
            for (int i = 0; i < 4; ++i)
                #pragma unroll
                for (int j = 0; j < 4; ++j) acc[i][j] += a[i] * b[j];
        }
        __syncthreads();
    }
    float* zo = zbuf + (size_t)d * NW * GATES;
    #pragma unroll
    for (int i = 0; i < 4; ++i)
        #pragma unroll
        for (int j = 0; j < 4; ++j)
            zo[(size_t)(row0 + ty * 4 + i) * GATES + (col0 + tx * 4 + j)] = acc[i][j];
}

// ---------------- char LSTM pointwise: gates -> c,h, write enc ----------------
__global__ __launch_bounds__(256)
void char_pointwise(int s,
    const float* __restrict__ zbuf,
    const float* __restrict__ b_f, const float* __restrict__ b_b,
    float* __restrict__ hbuf,   // [par][dir][NW][H2]
    float* __restrict__ cbuf,   // [dir][NW][H2]
    float* __restrict__ enc)    // [TC][NW][HID]
{
    int id = blockIdx.x * blockDim.x + threadIdx.x;   // 2*NW*H2
    int d = id >> 18;
    int r = id & ((1 << 18) - 1);
    int n = r >> 8, j = r & (H2 - 1);
    const float* bias = d ? b_b : b_f;
    const float* z = zbuf + ((size_t)d * NW + n) * GATES;
    float zi = z[j]         + bias[j];
    float zf = z[H2 + j]    + bias[H2 + j];
    float zg = z[2*H2 + j]  + bias[2*H2 + j];
    float zo = z[3*H2 + j]  + bias[3*H2 + j];
    float c_old = (s == 0) ? 0.f : cbuf[(size_t)d * NW * H2 + r];
    float c = sigf(zf) * c_old + sigf(zi) * tanhf(zg);
    float h = sigf(zo) * tanhf(c);
    cbuf[(size_t)d * NW * H2 + r] = c;
    hbuf[(size_t)(((s + 1) & 1) * 2 + d) * NW * H2 + r] = h;
    int t_time = d ? (TC - 1 - s) : s;
    enc[((size_t)t_time * NW + n) * HID + d * H2 + j] = h;
}

// ---------------- attention score GEMM: part[r][by] = sum over 64 cols of tanh(enc·aW+ab)*aw ----------------
__global__ __launch_bounds__(256)
void score_gemm(const float* __restrict__ enc, const float* __restrict__ aW,
                const float* __restrict__ ab, const float* __restrict__ aw,
                float* __restrict__ part)   // [TC*NW][8]
{
    __shared__ float As[16][65];
    __shared__ float Bs[16][65];
    __shared__ float red[64][17];
    const int tid = threadIdx.x;
    const int tx = tid & 15, ty = tid >> 4;
    const int row0 = blockIdx.x * 64;
    const int col0 = blockIdx.y * 64;
    float acc[4][4] = {};
    for (int kb = 0; kb < HID; kb += 16) {
        #pragma unroll
        for (int q = 0; q < 4; ++q) {
            int idx = tid + q * 256;
            int mm = idx >> 4, kk = idx & 15;
            As[kk][mm] = enc[(size_t)(row0 + mm) * HID + kb + kk];
            Bs[kk][mm] = aW[(size_t)(col0 + mm) * HID + kb + kk];
        }
        __syncthreads();
        #pragma unroll
        for (int kk = 0; kk < 16; ++kk) {
            float a[4], b[4];
            #pragma unroll
            for (int i = 0; i < 4; ++i) a[i] = As[kk][ty * 4 + i];
            #pragma unroll
            for (int j = 0; j < 4; ++j) b[j] = Bs[kk][tx * 4 + j];
            #pragma unroll
            for (int i = 0; i < 4; ++i)
                #pragma unroll
                for (int j = 0; j < 4; ++j) acc[i][j] += a[i] * b[j];
        }
        __syncthreads();
    }
    #pragma unroll
    for (int i = 0; i < 4; ++i) {
        float rs = 0.f;
        #pragma unroll
        for (int j = 0; j < 4; ++j) {
            int col = col0 + tx * 4 + j;
            rs += tanhf(acc[i][j] + ab[col]) * aw[col];
        }
        red[ty * 4 + i][tx] = rs;
    }
    __syncthreads();
    if (tid < 64) {
        float v = 0.f;
        #pragma unroll
        for (int x = 0; x < 16; ++x) v += red[tid][x];
        part[(size_t)(row0 + tid) * 8 + blockIdx.y] = v;
    }
}

// ---------------- softmax over t per word ----------------
__global__ void alpha_softmax(const float* __restrict__ part, float* __restrict__ al)
{
    int n = blockIdx.x * blockDim.x + threadIdx.x;   // NW
    float sc[TC];
    #pragma unroll
    for (int t = 0; t < TC; ++t) {
        float v = 0.f;
        #pragma unroll
        for (int q = 0; q < 8; ++q) v += part[(size_t)(t * NW + n) * 8 + q];
        sc[t] = v;
    }
    float m = -1e30f;
    #pragma unroll
    for (int t = 0; t < TC; ++t) m = fmaxf(m, sc[t]);
    float ssum = 0.f;
    #pragma unroll
    for (int t = 0; t < TC; ++t) { sc[t] = expf(sc[t] - m); ssum += sc[t]; }
    float inv = 1.f / ssum;
    #pragma unroll
    for (int t = 0; t < TC; ++t) al[t * NW + n] = sc[t] * inv;
}

// ---------------- context[n][h] = sum_t alpha[t][n]*enc[t][n][h] ----------------
__global__ void context_kernel(const float* __restrict__ al, const float* __restrict__ enc,
                               float* __restrict__ ctx)
{
    int id = blockIdx.x * blockDim.x + threadIdx.x;   // NW*HID
    int n = id >> 9, h = id & (HID - 1);
    float v = 0.f;
    #pragma unroll
    for (int t = 0; t < TC; ++t)
        v += al[t * NW + n] * enc[((size_t)t * NW + n) * HID + h];
    ctx[id] = v;
}

// ---------------- word input-projection GEMM: Gw[d][n][g] = xw[n]·Wih[g] + b[g] ----------------
__global__ __launch_bounds__(256)
void word_proj_gemm(const float* __restrict__ word_emb, const int* __restrict__ word_seq,
                    const float* __restrict__ ctx,
                    const float* __restrict__ Wih_f, const float* __restrict__ b_fp,
                    const float* __restrict__ Wih_b, const float* __restrict__ b_bp,
                    float* __restrict__ Gw)   // [dir][NW][GATES]
{
    const int d = blockIdx.z;
    const float* W = d ? Wih_b : Wih_f;
    const float* bias = d ? b_bp : b_fp;
    __shared__ float As[16][65];
    __shared__ float Bs[16][65];
    const int tid = threadIdx.x;
    const int tx = tid & 15, ty = tid >> 4;
    const int row0 = blockIdx.x * 64;
    const int col0 = blockIdx.y * 64;
    float acc[4][4] = {};
    for (int kb = 0; kb < KW; kb += 16) {
        #pragma unroll
        for (int q = 0; q < 4; ++q) {
            int idx = tid + q * 256;
            int mm = idx >> 4, kk = idx & 15;
            int k = kb + kk;
            int n = row0 + mm;
            float av = 0.f, bv = 0.f;
            if (k < KW) {
                if (k < EW) av = word_emb[(size_t)word_seq[n] * EW + k];
                else        av = ctx[(size_t)n * HID + (k - EW)];
                bv = W[(size_t)(col0 + mm) * KW + k];
            }
            As[kk][mm] = av;
            Bs[kk][mm] = bv;
        }
        __syncthreads();
        #pragma unroll
        for (int kk = 0; kk < 16; ++kk) {
            float a[4], b[4];
            #pragma unroll
            for (int i = 0; i < 4; ++i) a[i] = As[kk][ty * 4 + i];
            #pragma unroll
            for (int j = 0; j < 4; ++j) b[j] = Bs[kk][tx * 4 + j];
            #pragma unroll
            for (int i = 0; i < 4; ++i)
                #pragma unroll
                for (int j = 0; j < 4; ++j) acc[i][j] += a[i] * b[j];
        }
        __syncthreads();
    }
    float* zo = Gw + (size_t)d * NW * GATES;
    #pragma unroll
    for (int i = 0; i < 4; ++i)
        #pragma unroll
        for (int j = 0; j < 4; ++j) {
            int g = col0 + tx * 4 + j;
            zo[(size_t)(row0 + ty * 4 + i) * GATES + g] = acc[i][j] + bias[g];
        }
}

// ---------------- word BiLSTM persistent recurrence ----------------
// 16 blocks: blocks 0..7 = forward, 8..15 = backward; each owns 32 hidden units.
__global__ __launch_bounds__(256)
void word_lstm(const float* __restrict__ Whh_f, const float* __restrict__ Whh_b,
               const float* __restrict__ Gw,     // [dir][NW][GATES]
               float* __restrict__ hglob,        // [dir][par][H2]
               float* __restrict__ wout,         // [NW][HID]
               unsigned int* __restrict__ bar)   // [NW]
{
    const int b = blockIdx.x;
    const int d = b >> 3;
    const int j0 = (b & 7) * 32;
    const int tid = threadIdx.x;
    const int gl = tid >> 1, kh = tid & 1;
    const int gt = gl >> 5, u = gl & 31;
    const int grow = gt * H2 + j0 + u;
    const float* Whh = d ? Whh_b : Whh_f;
    const float* G = Gw + (size_t)d * NW * GATES;

    float w[128];
    #pragma unroll
    for (int kk = 0; kk < 128; ++kk) w[kk] = Whh[(size_t)grow * H2 + kh * 128 + kk];

    __shared__ float hs[H2];
    __shared__ float zs[128];
    float c = 0.f;

    for (int t = 0; t < NW; ++t) {
        const int par = t & 1;
        hs[tid] = (t == 0) ? 0.f : hglob[(d * 2 + par) * H2 + tid];
        __syncthreads();
        float acc = 0.f;
        const float* hb = hs + kh * 128;
        #pragma unroll
        for (int kk = 0; kk < 128; ++kk) acc += hb[kk] * w[kk];
        acc += __shfl_xor(acc, 1);
        const int t_time = d ? (NW - 1 - t) : t;
        if (kh == 0) zs[gl] = acc + G[(size_t)t_time * GATES + grow];
        __syncthreads();
        if (tid < 32) {
            float zi = zs[tid], zf = zs[32 + tid], zg = zs[64 + tid], zo = zs[96 + tid];
            c = sigf(zf) * c + sigf(zi) * tanhf(zg);
            float h = sigf(zo) * tanhf(c);
            int j = j0 + tid;
            hglob[(d * 2 + ((t + 1) & 1)) * H2 + j] = h;
            wout[(size_t)t_time * HID + d * H2 + j] = h;
            __threadfence();
        }
        __syncthreads();
        if (tid == 0) {
            __hip_atomic_fetch_add(&bar[t], 1u, __ATOMIC_RELEASE, __HIP_MEMORY_SCOPE_AGENT);
            while (__hip_atomic_load(&bar[t], __ATOMIC_ACQUIRE, __HIP_MEMORY_SCOPE_AGENT) < 16u) {}
        }
        __syncthreads();
    }
}

// ---------------- output heads: log_softmax(out·hpW^T+hpb), log_softmax(out·hnW^T+hnb) ----------------
__global__ __launch_bounds__(64)
void heads_kernel(const float* __restrict__ wout,
                  const float* __restrict__ hpW, const float* __restrict__ hpb,
                  const float* __restrict__ hnW, const float* __restrict__ hnb,
                  float* __restrict__ out)
{
    const int n = blockIdx.x;
    const int tid = threadIdx.x;
    __shared__ float v[HID];
    #pragma unroll
    for (int q = 0; q < 8; ++q) v[tid + q * 64] = wout[(size_t)n * HID + tid + q * 64];
    __syncthreads();
    float sc = 0.f;
    if (tid < NPOS) {
        for (int k = 0; k < HID; ++k) sc += v[k] * hpW[(size_t)tid * HID + k];
        sc += hpb[tid];
    } else {
        int cc = tid - NPOS;
        for (int k = 0; k < HID; ++k) sc += v[k] * hnW[(size_t)cc * HID + k];
        sc += hnb[cc];
    }
    __shared__ float ssc[64];
    __shared__ float lsep, lsen;
    ssc[tid] = sc;
    __syncthreads();
    if (tid == 0) {
        float m = -1e30f;
        for (int i = 0; i < NPOS; ++i) m = fmaxf(m, ssc[i]);
        float su = 0.f;
        for (int i = 0; i < NPOS; ++i) su += expf(ssc[i] - m);
        lsep = m + logf(su);
    }
    if (tid == 32) {
        float m = -1e30f;
        for (int i = NPOS; i < 64; ++i) m = fmaxf(m, ssc[i]);
        float su = 0.f;
        for (int i = NPOS; i < 64; ++i) su += expf(ssc[i] - m);
        lsen = m + logf(su);
    }
    __syncthreads();
    if (tid < NPOS) out[(size_t)n * NPOS + tid] = sc - lsep;
    else            out[(size_t)NW * NPOS + (size_t)n * NNER + (tid - NPOS)] = sc - lsen;
}

// ---------------- host launch ----------------
extern "C" void kernel_launch(void* const* d_in, const int* in_sizes, int n_in,
                              void* d_out, int out_size, void* d_ws, size_t ws_size,
                              hipStream_t stream) {
    const float* char_emb = (const float*)d_in[0];
    const float* word_emb = (const float*)d_in[1];
    const float* cWih_f   = (const float*)d_in[2];
    const float* cWhh_f   = (const float*)d_in[3];
    const float* cb_f     = (const float*)d_in[4];
    const float* cWih_b   = (const float*)d_in[5];
    const float* cWhh_b   = (const float*)d_in[6];
    const float* cb_b     = (const float*)d_in[7];
    const float* wWih_f   = (const float*)d_in[8];
    const float* wWhh_f   = (const float*)d_in[9];
    const float* wb_f     = (const float*)d_in[10];
    const float* wWih_b   = (const float*)d_in[11];
    const float* wWhh_b   = (const float*)d_in[12];
    const float* wb_b     = (const float*)d_in[13];
    const float* aW       = (const float*)d_in[14];
    const float* ab       = (const float*)d_in[15];
    const float* aw       = (const float*)d_in[16];
    const float* hpW      = (const float*)d_in[17];
    const float* hpb      = (const float*)d_in[18];
    const float* hnW      = (const float*)d_in[19];
    const float* hnb      = (const float*)d_in[20];
    const int*   word_seq = (const int*)d_in[21];
    const int*   char_seq = (const int*)d_in[22];
    float* out = (float*)d_out;
    float* ws  = (float*)d_ws;

    // workspace layout (in floats)
    const size_t OFF_ENC  = 0;                         // 16*1024*512   = 8388608
    const size_t OFF_Z    = OFF_ENC  + (size_t)TC * NW * HID;     // 2*1024*1024 = 2097152
    const size_t OFF_CH   = OFF_Z    + (size_t)2 * NW * GATES;    // 2*2*1024*256 = 1048576
    const size_t OFF_CC   = OFF_CH   + (size_t)4 * NW * H2;       // 2*1024*256 = 524288
    const size_t OFF_CTX  = OFF_CC   + (size_t)2 * NW * H2;       // 1024*512
    const size_t OFF_WOUT = OFF_CTX  + (size_t)NW * HID;          // 1024*512
    const size_t OFF_PART = OFF_WOUT + (size_t)NW * HID;          // 16*1024*8
    const size_t OFF_AL   = OFF_PART + (size_t)TC * NW * 8;       // 16*1024
    const size_t OFF_WH   = OFF_AL   + (size_t)TC * NW;           // 2*2*256
    const size_t OFF_BAR  = OFF_WH   + 1024;                      // 1024 u32

    // zero the barrier slots (the only region that needs a fresh zero every call)
    hipMemsetAsync(ws + OFF_BAR, 0, NW * sizeof(unsigned int), stream);

    // --- char BiLSTM, 16 steps ---
    dim3 gchar(NW / 64, GATES / 64, 2);
    for (int s = 0; s < TC; ++s) {
        char_gate_gemm<<<gchar, 256, 0, stream>>>(s, char_emb, char_seq,
            cWih_f, cWhh_f, cWih_b, cWhh_b, ws + OFF_CH, ws + OFF_Z);
        char_pointwise<<<(2 * NW * H2) / 256, 256, 0, stream>>>(s, ws + OFF_Z,
            cb_f, cb_b, ws + OFF_CH, ws + OFF_CC, ws + OFF_ENC);
    }

    // --- attention ---
    score_gemm<<<dim3(TC * NW / 64, HID / 64), 256, 0, stream>>>(
        ws + OFF_ENC, aW, ab, aw, ws + OFF_PART);
    alpha_softmax<<<NW / 256, 256, 0, stream>>>(ws + OFF_PART, ws + OFF_AL);
    context_kernel<<<(NW * HID) / 256, 256, 0, stream>>>(ws + OFF_AL, ws + OFF_ENC, ws + OFF_CTX);

    // --- word input projection (reuses zbuf region as Gw) ---
    word_proj_gemm<<<dim3(NW / 64, GATES / 64, 2), 256, 0, stream>>>(
        word_emb, word_seq, ws + OFF_CTX, wWih_f, wb_f, wWih_b, wb_b, ws + OFF_Z);

    // --- word BiLSTM persistent recurrence ---
    word_lstm<<<16, 256, 0, stream>>>(wWhh_f, wWhh_b, ws + OFF_Z,
        ws + OFF_WH, ws + OFF_WOUT, (unsigned int*)(ws + OFF_BAR));

    // --- heads ---
    heads_kernel<<<NW, 64, 0, stream>>>(ws + OFF_WOUT, hpW, hpb, hnW, hnb, out);
}

// Round 2
// 4237.235 us; speedup vs baseline: 1.0695x; 1.0695x over previous
//
#include <hip/hip_runtime.h>
#include <hip/hip_bf16.h>
#include <hip/hip_fp16.h>
#include <math.h>

#define NW 1024
#define TC 16
#define EC 128
#define EW 300
#define HID 512
#define H2 256
#define GATES 1024
#define KC (EC + H2)   // 384
#define KW (EW + HID)  // 812
#define NPOS 48
#define NNER 16

typedef _Float16 h2v __attribute__((ext_vector_type(2)));
union U32H { unsigned int u; h2v h; float f; };

__device__ __forceinline__ float sigf(float x) { return 1.f / (1.f + expf(-x)); }

// ---------------- char LSTM gate GEMM: z[d][n][g] = x_t[n]·Wih[g] + h[n]·Whh[g] ----------------
__global__ __launch_bounds__(256)
void char_gate_gemm(int s,
    const float* __restrict__ char_emb, const int* __restrict__ char_seq,
    const float* __restrict__ Wih_f, const float* __restrict__ Whh_f,
    const float* __restrict__ Wih_b, const float* __restrict__ Whh_b,
    const float* __restrict__ hbuf,   // [par][dir][NW][H2]
    float* __restrict__ zbuf)         // [dir][NW][GATES]
{
    const int d = blockIdx.z;
    const float* Wih = d ? Wih_b : Wih_f;
    const float* Whh = d ? Whh_b : Whh_f;
    const int t_time = d ? (TC - 1 - s) : s;
    const float* hprev = hbuf + (size_t)((s & 1) * 2 + d) * NW * H2;

    __shared__ float As[16][65];
    __shared__ float Bs[16][65];
    const int tid = threadIdx.x;
    const int tx = tid & 15, ty = tid >> 4;
    const int row0 = blockIdx.x * 64;
    const int col0 = blockIdx.y * 64;
    float acc[4][4] = {};
    for (int kb = 0; kb < KC; kb += 16) {
        #pragma unroll
        for (int q = 0; q < 4; ++q) {
            int idx = tid + q * 256;
            int mm = idx >> 4, kk = idx & 15;
            int k = kb + kk;
            int n = row0 + mm;
            float av;
            if (k < EC) {
                int ci = char_seq[n * TC + t_time];
                av = char_emb[(size_t)ci * EC + k];
            } else {
                av = (s == 0) ? 0.f : hprev[(size_t)n * H2 + (k - EC)];
            }
            As[kk][mm] = av;
            int g = col0 + mm;
            Bs[kk][mm] = (k < EC) ? Wih[(size_t)g * EC + k] : Whh[(size_t)g * H2 + (k - EC)];
        }
        __syncthreads();
        #pragma unroll
        for (int kk = 0; kk < 16; ++kk) {
            float a[4], b[4];
            #pragma unroll
            for (int i = 0; i < 4; ++i) a[i] = As[kk][ty * 4 + i];
            #pragma unroll
            for (int j = 0; j < 4; ++j) b[j] = Bs[kk][tx * 4 + j];
            #pragma unroll
            for (int i = 0; i < 4; ++i)
                #pragma unroll
                for (int j = 0; j < 4; ++j) acc[i][j] += a[i] * b[j];
        }
        __syncthreads();
    }
    float* zo = zbuf + (size_t)d * NW * GATES;
    #pragma unroll
    for (int i = 0; i < 4; ++i)
        #pragma unroll
        for (int j = 0; j < 4; ++j)
            zo[(size_t)(row0 + ty * 4 + i) * GATES + (col0 + tx * 4 + j)] = acc[i][j];
}

// ---------------- char LSTM pointwise: gates -> c,h, write enc ----------------
__global__ __launch_bounds__(256)
void char_pointwise(int s,
    const float* __restrict__ zbuf,
    const float* __restrict__ b_f, const float* __restrict__ b_b,
    float* __restrict__ hbuf,   // [par][dir][NW][H2]
    float* __restrict__ cbuf,   // [dir][NW][H2]
    float* __restrict__ enc)    // [TC][NW][HID]
{
    int id = blockIdx.x * blockDim.x + threadIdx.x;   // 2*NW*H2
    int d = id >> 18;
    int r = id & ((1 << 18) - 1);
    int n = r >> 8, j = r & (H2 - 1);
    const float* bias = d ? b_b : b_f;
    const float* z = zbuf + ((size_t)d * NW + n) * GATES;
    float zi = z[j]         + bias[j];
    float zf = z[H2 + j]    + bias[H2 + j];
    float zg = z[2*H2 + j]  + bias[2*H2 + j];
    float zo = z[3*H2 + j]  + bias[3*H2 + j];
    float c_old = (s == 0) ? 0.f : cbuf[(size_t)d * NW * H2 + r];
    float c = sigf(zf) * c_old + sigf(zi) * tanhf(zg);
    float h = sigf(zo) * tanhf(c);
    cbuf[(size_t)d * NW * H2 + r] = c;
    hbuf[(size_t)(((s + 1) & 1) * 2 + d) * NW * H2 + r] = h;
    int t_time = d ? (TC - 1 - s) : s;
    enc[((size_t)t_time * NW + n) * HID + d * H2 + j] = h;
}

// ---------------- attention score GEMM ----------------
__global__ __launch_bounds__(256)
void score_gemm(const float* __restrict__ enc, const float* __restrict__ aW,
                const float* __restrict__ ab, const float* __restrict__ aw,
                float* __restrict__ part)   // [TC*NW][8]
{
    __shared__ float As[16][65];
    __shared__ float Bs[16][65];
    __shared__ float red[64][17];
    const int tid = threadIdx.x;
    const int tx = tid & 15, ty = tid >> 4;
    const int row0 = blockIdx.x * 64;
    const int col0 = blockIdx.y * 64;
    float acc[4][4] = {};
    for (int kb = 0; kb < HID; kb += 16) {
        #pragma unroll
        for (int q = 0; q < 4; ++q) {
            int idx = tid + q * 256;
            int mm = idx >> 4, kk = idx & 15;
            As[kk][mm] = enc[(size_t)(row0 + mm) * HID + kb + kk];
            Bs[kk][mm] = aW[(size_t)(col0 + mm) * HID + kb + kk];
        }
        __syncthreads();
        #pragma unroll
        for (int kk = 0; kk < 16; ++kk) {
            float a[4], b[4];
            #pragma unroll
            for (int i = 0; i < 4; ++i) a[i] = As[kk][ty * 4 + i];
            #pragma unroll
            for (int j = 0; j < 4; ++j) b[j] = Bs[kk][tx * 4 + j];
            #pragma unroll
            for (int i = 0; i < 4; ++i)
                #pragma unroll
                for (int j = 0; j < 4; ++j) acc[i][j] += a[i] * b[j];
        }
        __syncthreads();
    }
    #pragma unroll
    for (int i = 0; i < 4; ++i) {
        float rs = 0.f;
        #pragma unroll
        for (int j = 0; j < 4; ++j) {
            int col = col0 + tx * 4 + j;
            rs += tanhf(acc[i][j] + ab[col]) * aw[col];
        }
        red[ty * 4 + i][tx] = rs;
    }
    __syncthreads();
    if (tid < 64) {
        float v = 0.f;
        #pragma unroll
        for (int x = 0; x < 16; ++x) v += red[tid][x];
        part[(size_t)(row0 + tid) * 8 + blockIdx.y] = v;
    }
}

// ---------------- softmax over t per word ----------------
__global__ void alpha_softmax(const float* __restrict__ part, float* __restrict__ al)
{
    int n = blockIdx.x * blockDim.x + threadIdx.x;   // NW
    float sc[TC];
    #pragma unroll
    for (int t = 0; t < TC; ++t) {
        float v = 0.f;
        #pragma unroll
        for (int q = 0; q < 8; ++q) v += part[(size_t)(t * NW + n) * 8 + q];
        sc[t] = v;
    }
    float m = -1e30f;
    #pragma unroll
    for (int t = 0; t < TC; ++t) m = fmaxf(m, sc[t]);
    float ssum = 0.f;
    #pragma unroll
    for (int t = 0; t < TC; ++t) { sc[t] = expf(sc[t] - m); ssum += sc[t]; }
    float inv = 1.f / ssum;
    #pragma unroll
    for (int t = 0; t < TC; ++t) al[t * NW + n] = sc[t] * inv;
}

// ---------------- context ----------------
__global__ void context_kernel(const float* __restrict__ al, const float* __restrict__ enc,
                               float* __restrict__ ctx)
{
    int id = blockIdx.x * blockDim.x + threadIdx.x;   // NW*HID
    int n = id >> 9, h = id & (HID - 1);
    float v = 0.f;
    #pragma unroll
    for (int t = 0; t < TC; ++t)
        v += al[t * NW + n] * enc[((size_t)t * NW + n) * HID + h];
    ctx[id] = v;
}

// ---------------- word input-projection GEMM ----------------
__global__ __launch_bounds__(256)
void word_proj_gemm(const float* __restrict__ word_emb, const int* __restrict__ word_seq,
                    const float* __restrict__ ctx,
                    const float* __restrict__ Wih_f, const float* __restrict__ b_fp,
                    const float* __restrict__ Wih_b, const float* __restrict__ b_bp,
                    float* __restrict__ Gw)   // [dir][NW][GATES]
{
    const int d = blockIdx.z;
    const float* W = d ? Wih_b : Wih_f;
    const float* bias = d ? b_bp : b_fp;
    __shared__ float As[16][65];
    __shared__ float Bs[16][65];
    const int tid = threadIdx.x;
    const int tx = tid & 15, ty = tid >> 4;
    const int row0 = blockIdx.x * 64;
    const int col0 = blockIdx.y * 64;
    float acc[4][4] = {};
    for (int kb = 0; kb < KW; kb += 16) {
        #pragma unroll
        for (int q = 0; q < 4; ++q) {
            int idx = tid + q * 256;
            int mm = idx >> 4, kk = idx & 15;
            int k = kb + kk;
            int n = row0 + mm;
            float av = 0.f, bv = 0.f;
            if (k < KW) {
                if (k < EW) av = word_emb[(size_t)word_seq[n] * EW + k];
                else        av = ctx[(size_t)n * HID + (k - EW)];
                bv = W[(size_t)(col0 + mm) * KW + k];
            }
            As[kk][mm] = av;
            Bs[kk][mm] = bv;
        }
        __syncthreads();
        #pragma unroll
        for (int kk = 0; kk < 16; ++kk) {
            float a[4], b[4];
            #pragma unroll
            for (int i = 0; i < 4; ++i) a[i] = As[kk][ty * 4 + i];
            #pragma unroll
            for (int j = 0; j < 4; ++j) b[j] = Bs[kk][tx * 4 + j];
            #pragma unroll
            for (int i = 0; i < 4; ++i)
                #pragma unroll
                for (int j = 0; j < 4; ++j) acc[i][j] += a[i] * b[j];
        }
        __syncthreads();
    }
    float* zo = Gw + (size_t)d * NW * GATES;
    #pragma unroll
    for (int i = 0; i < 4; ++i)
        #pragma unroll
        for (int j = 0; j < 4; ++j) {
            int g = col0 + tx * 4 + j;
            zo[(size_t)(row0 + ty * 4 + i) * GATES + g] = acc[i][j] + bias[g];
        }
}

// ---------------- word BiLSTM: one persistent block per direction, no global sync ----------------
// 512 threads. Thread owns gate rows {tid, 512+tid}. Whh packed fp16:
// pairs 0..95 in VGPRs, pairs 96..127 in LDS. h packed half2 in LDS (broadcast reads).
__global__ __launch_bounds__(512, 2)
void word_lstm_dir(const float* __restrict__ Whh_fw, const float* __restrict__ Whh_bw,
                   const float* __restrict__ Gw,     // [dir][NW][GATES]
                   float* __restrict__ wout)         // [NW][HID]
{
    extern __shared__ float smem[];
    unsigned int* lw = (unsigned int*)smem;            // [64 slots][512] packed half2
    float* zs = smem + 64 * 512;                       // [1024]
    unsigned int* hpk = (unsigned int*)(zs + GATES);   // [128] packed half2

    const int d = blockIdx.x;
    const int tid = threadIdx.x;
    const float* Whh = d ? Whh_bw : Whh_fw;
    const float* G = Gw + (size_t)d * NW * GATES;

    const float* r0 = Whh + (size_t)tid * H2;
    const float* r1 = Whh + (size_t)(tid + 512) * H2;
    h2v wv0[96], wv1[96];
    #pragma unroll
    for (int p = 0; p < 96; ++p) {
        h2v w; w.x = (_Float16)r0[2*p]; w.y = (_Float16)r0[2*p+1]; wv0[p] = w;
        h2v v; v.x = (_Float16)r1[2*p]; v.y = (_Float16)r1[2*p+1]; wv1[p] = v;
    }
    #pragma unroll
    for (int p = 96; p < 128; ++p) {
        U32H a; a.h.x = (_Float16)r0[2*p]; a.h.y = (_Float16)r0[2*p+1];
        lw[(p - 96) * 512 + tid] = a.u;
        U32H b; b.h.x = (_Float16)r1[2*p]; b.h.y = (_Float16)r1[2*p+1];
        lw[(p - 96 + 32) * 512 + tid] = b.u;
    }
    if (tid < 128) hpk[tid] = 0u;
    float c0 = 0.f, c1 = 0.f;
    __syncthreads();

    const int woff = d * H2;
    for (int t = 0; t < NW; ++t) {
        const int tt = d ? (NW - 1 - t) : t;
        float g0 = G[(size_t)tt * GATES + tid];
        float g1 = G[(size_t)tt * GATES + 512 + tid];
        float acc0 = 0.f, acc1 = 0.f;
        const uint4* hp4 = (const uint4*)hpk;
        #pragma unroll
        for (int q = 0; q < 32; ++q) {
            uint4 hh = hp4[q];
            #pragma unroll
            for (int r = 0; r < 4; ++r) {
                const int p = q * 4 + r;
                U32H hu; hu.u = (&hh.x)[r];
                h2v w0, w1;
                if (p < 96) { w0 = wv0[p]; w1 = wv1[p]; }
                else {
                    U32H a; a.u = lw[(p - 96) * 512 + tid]; w0 = a.h;
                    U32H b; b.u = lw[(p - 96 + 32) * 512 + tid]; w1 = b.h;
                }
                acc0 = __builtin_amdgcn_fdot2(hu.h, w0, acc0, false);
                acc1 = __builtin_amdgcn_fdot2(hu.h, w1, acc1, false);
            }
        }
        zs[tid] = acc0 + g0;
        zs[512 + tid] = acc1 + g1;
        __syncthreads();
        if (tid < 128) {
            const int u0 = 2 * tid, u1 = u0 + 1;
            float zi0 = zs[u0],       zi1 = zs[u1];
            float zf0 = zs[256 + u0], zf1 = zs[256 + u1];
            float zg0 = zs[512 + u0], zg1 = zs[512 + u1];
            float zo0 = zs[768 + u0], zo1 = zs[768 + u1];
            c0 = sigf(zf0) * c0 + sigf(zi0) * tanhf(zg0);
            float h0 = sigf(zo0) * tanhf(c0);
            c1 = sigf(zf1) * c1 + sigf(zi1) * tanhf(zg1);
            float h1 = sigf(zo1) * tanhf(c1);
            U32H hp; hp.h.x = (_Float16)h0; hp.h.y = (_Float16)h1;
            hpk[tid] = hp.u;
            float2 hv; hv.x = h0; hv.y = h1;
            *(float2*)&wout[(size_t)tt * HID + woff + u0] = hv;
        }
        __syncthreads();
    }
}

// ---------------- output heads ----------------
__global__ __launch_bounds__(64)
void heads_kernel(const float* __restrict__ wout,
                  const float* __restrict__ hpW, const float* __restrict__ hpb,
                  const float* __restrict__ hnW, const float* __restrict__ hnb,
                  float* __restrict__ out)
{
    const int n = blockIdx.x;
    const int tid = threadIdx.x;
    __shared__ float v[HID];
    #pragma unroll
    for (int q = 0; q < 8; ++q) v[tid + q * 64] = wout[(size_t)n * HID + tid + q * 64];
    __syncthreads();
    float sc = 0.f;
    if (tid < NPOS) {
        for (int k = 0; k < HID; ++k) sc += v[k] * hpW[(size_t)tid * HID + k];
        sc += hpb[tid];
    } else {
        int cc = tid - NPOS;
        for (int k = 0; k < HID; ++k) sc += v[k] * hnW[(size_t)cc * HID + k];
        sc += hnb[cc];
    }
    __shared__ float ssc[64];
    __shared__ float lsep, lsen;
    ssc[tid] = sc;
    __syncthreads();
    if (tid == 0) {
        float m = -1e30f;
        for (int i = 0; i < NPOS; ++i) m = fmaxf(m, ssc[i]);
        float su = 0.f;
        for (int i = 0; i < NPOS; ++i) su += expf(ssc[i] - m);
        lsep = m + logf(su);
    }
    if (tid == 32) {
        float m = -1e30f;
        for (int i = NPOS; i < 64; ++i) m = fmaxf(m, ssc[i]);
        float su = 0.f;
        for (int i = NPOS; i < 64; ++i) su += expf(ssc[i] - m);
        lsen = m + logf(su);
    }
    __syncthreads();
    if (tid < NPOS) out[(size_t)n * NPOS + tid] = sc - lsep;
    else            out[(size_t)NW * NPOS + (size_t)n * NNER + (tid - NPOS)] = sc - lsen;
}

// ---------------- host launch ----------------
extern "C" void kernel_launch(void* const* d_in, const int* in_sizes, int n_in,
                              void* d_out, int out_size, void* d_ws, size_t ws_size,
                              hipStream_t stream) {
    const float* char_emb = (const float*)d_in[0];
    const float* word_emb = (const float*)d_in[1];
    const float* cWih_f   = (const float*)d_in[2];
    const float* cWhh_f   = (const float*)d_in[3];
    const float* cb_f     = (const float*)d_in[4];
    const float* cWih_b   = (const float*)d_in[5];
    const float* cWhh_b   = (const float*)d_in[6];
    const float* cb_b     = (const float*)d_in[7];
    const float* wWih_f   = (const float*)d_in[8];
    const float* wWhh_f   = (const float*)d_in[9];
    const float* wb_f     = (const float*)d_in[10];
    const float* wWih_b   = (const float*)d_in[11];
    const float* wWhh_b   = (const float*)d_in[12];
    const float* wb_b     = (const float*)d_in[13];
    const float* aW       = (const float*)d_in[14];
    const float* ab       = (const float*)d_in[15];
    const float* aw       = (const float*)d_in[16];
    const float* hpW      = (const float*)d_in[17];
    const float* hpb      = (const float*)d_in[18];
    const float* hnW      = (const float*)d_in[19];
    const float* hnb      = (const float*)d_in[20];
    const int*   word_seq = (const int*)d_in[21];
    const int*   char_seq = (const int*)d_in[22];
    float* out = (float*)d_out;
    float* ws  = (float*)d_ws;

    const size_t OFF_ENC  = 0;
    const size_t OFF_Z    = OFF_ENC  + (size_t)TC * NW * HID;
    const size_t OFF_CH   = OFF_Z    + (size_t)2 * NW * GATES;
    const size_t OFF_CC   = OFF_CH   + (size_t)4 * NW * H2;
    const size_t OFF_CTX  = OFF_CC   + (size_t)2 * NW * H2;
    const size_t OFF_WOUT = OFF_CTX  + (size_t)NW * HID;
    const size_t OFF_PART = OFF_WOUT + (size_t)NW * HID;
    const size_t OFF_AL   = OFF_PART + (size_t)TC * NW * 8;

    // --- char BiLSTM, 16 steps ---
    dim3 gchar(NW / 64, GATES / 64, 2);
    for (int s = 0; s < TC; ++s) {
        char_gate_gemm<<<gchar, 256, 0, stream>>>(s, char_emb, char_seq,
            cWih_f, cWhh_f, cWih_b, cWhh_b, ws + OFF_CH, ws + OFF_Z);
        char_pointwise<<<(2 * NW * H2) / 256, 256, 0, stream>>>(s, ws + OFF_Z,
            cb_f, cb_b, ws + OFF_CH, ws + OFF_CC, ws + OFF_ENC);
    }

    // --- attention ---
    score_gemm<<<dim3(TC * NW / 64, HID / 64), 256, 0, stream>>>(
        ws + OFF_ENC, aW, ab, aw, ws + OFF_PART);
    alpha_softmax<<<NW / 256, 256, 0, stream>>>(ws + OFF_PART, ws + OFF_AL);
    context_kernel<<<(NW * HID) / 256, 256, 0, stream>>>(ws + OFF_AL, ws + OFF_ENC, ws + OFF_CTX);

    // --- word input projection ---
    word_proj_gemm<<<dim3(NW / 64, GATES / 64, 2), 256, 0, stream>>>(
        word_emb, word_seq, ws + OFF_CTX, wWih_f, wb_f, wWih_b, wb_b, ws + OFF_Z);

    // --- word BiLSTM: 2 independent persistent blocks, 135680 B dynamic LDS each ---
    const int lds_bytes = (64 * 512 + GATES + 128) * 4;   // 135680
    hipFuncSetAttribute((const void*)word_lstm_dir,
                        hipFuncAttributeMaxDynamicSharedMemorySize, lds_bytes);
    word_lstm_dir<<<2, 512, lds_bytes, stream>>>(wWhh_f, wWhh_b, ws + OFF_Z, ws + OFF_WOUT);

    // --- heads ---
    heads_kernel<<<NW, 64, 0, stream>>>(ws + OFF_WOUT, hpW, hpb, hnW, hnb, out);
}

// Round 3
// 3623.362 us; speedup vs baseline: 1.2507x; 1.1694x over previous
//
#include <hip/hip_runtime.h>
#include <hip/hip_bf16.h>
#include <hip/hip_fp16.h>
#include <math.h>

#define NW 1024
#define TC 16
#define EC 128
#define EW 300
#define HID 512
#define H2 256
#define GATES 1024
#define KC (EC + H2)   // 384
#define KW (EW + HID)  // 812
#define NPOS 48
#define NNER 16

typedef _Float16 h2v __attribute__((ext_vector_type(2)));
union U32H { unsigned int u; h2v h; float f; };

__device__ __forceinline__ float sigf(float x) { return 1.f / (1.f + expf(-x)); }

// ---------------- char LSTM gate GEMM: z[d][n][g] = x_t[n]·Wih[g] + h[n]·Whh[g] ----------------
__global__ __launch_bounds__(256)
void char_gate_gemm(int s,
    const float* __restrict__ char_emb, const int* __restrict__ char_seq,
    const float* __restrict__ Wih_f, const float* __restrict__ Whh_f,
    const float* __restrict__ Wih_b, const float* __restrict__ Whh_b,
    const float* __restrict__ hbuf,   // [par][dir][NW][H2]
    float* __restrict__ zbuf)         // [dir][NW][GATES]
{
    const int d = blockIdx.z;
    const float* Wih = d ? Wih_b : Wih_f;
    const float* Whh = d ? Whh_b : Whh_f;
    const int t_time = d ? (TC - 1 - s) : s;
    const float* hprev = hbuf + (size_t)((s & 1) * 2 + d) * NW * H2;

    __shared__ float As[16][65];
    __shared__ float Bs[16][65];
    const int tid = threadIdx.x;
    const int tx = tid & 15, ty = tid >> 4;
    const int row0 = blockIdx.x * 64;
    const int col0 = blockIdx.y * 64;
    float acc[4][4] = {};
    for (int kb = 0; kb < KC; kb += 16) {
        #pragma unroll
        for (int q = 0; q < 4; ++q) {
            int idx = tid + q * 256;
            int mm = idx >> 4, kk = idx & 15;
            int k = kb + kk;
            int n = row0 + mm;
            float av;
            if (k < EC) {
                int ci = char_seq[n * TC + t_time];
                av = char_emb[(size_t)ci * EC + k];
            } else {
                av = (s == 0) ? 0.f : hprev[(size_t)n * H2 + (k - EC)];
            }
            As[kk][mm] = av;
            int g = col0 + mm;
            Bs[kk][mm] = (k < EC) ? Wih[(size_t)g * EC + k] : Whh[(size_t)g * H2 + (k - EC)];
        }
        __syncthreads();
        #pragma unroll
        for (int kk = 0; kk < 16; ++kk) {
            float a[4], b[4];
            #pragma unroll
            for (int i = 0; i < 4; ++i) a[i] = As[kk][ty * 4 + i];
            #pragma unroll
            for (int j = 0; j < 4; ++j) b[j] = Bs[kk][tx * 4 + j];
            #pragma unroll
            for (int i = 0; i < 4; ++i)
                #pragma unroll
                for (int j = 0; j < 4; ++j) acc[i][j] += a[i] * b[j];
        }
        __syncthreads();
    }
    float* zo = zbuf + (size_t)d * NW * GATES;
    #pragma unroll
    for (int i = 0; i < 4; ++i)
        #pragma unroll
        for (int j = 0; j < 4; ++j)
            zo[(size_t)(row0 + ty * 4 + i) * GATES + (col0 + tx * 4 + j)] = acc[i][j];
}

// ---------------- char LSTM pointwise: gates -> c,h, write enc ----------------
__global__ __launch_bounds__(256)
void char_pointwise(int s,
    const float* __restrict__ zbuf,
    const float* __restrict__ b_f, const float* __restrict__ b_b,
    float* __restrict__ hbuf,   // [par][dir][NW][H2]
    float* __restrict__ cbuf,   // [dir][NW][H2]
    float* __restrict__ enc)    // [TC][NW][HID]
{
    int id = blockIdx.x * blockDim.x + threadIdx.x;   // 2*NW*H2
    int d = id >> 18;
    int r = id & ((1 << 18) - 1);
    int n = r >> 8, j = r & (H2 - 1);
    const float* bias = d ? b_b : b_f;
    const float* z = zbuf + ((size_t)d * NW + n) * GATES;
    float zi = z[j]         + bias[j];
    float zf = z[H2 + j]    + bias[H2 + j];
    float zg = z[2*H2 + j]  + bias[2*H2 + j];
    float zo = z[3*H2 + j]  + bias[3*H2 + j];
    float c_old = (s == 0) ? 0.f : cbuf[(size_t)d * NW * H2 + r];
    float c = sigf(zf) * c_old + sigf(zi) * tanhf(zg);
    float h = sigf(zo) * tanhf(c);
    cbuf[(size_t)d * NW * H2 + r] = c;
    hbuf[(size_t)(((s + 1) & 1) * 2 + d) * NW * H2 + r] = h;
    int t_time = d ? (TC - 1 - s) : s;
    enc[((size_t)t_time * NW + n) * HID + d * H2 + j] = h;
}

// ---------------- attention score GEMM ----------------
__global__ __launch_bounds__(256)
void score_gemm(const float* __restrict__ enc, const float* __restrict__ aW,
                const float* __restrict__ ab, const float* __restrict__ aw,
                float* __restrict__ part)   // [TC*NW][8]
{
    __shared__ float As[16][65];
    __shared__ float Bs[16][65];
    __shared__ float red[64][17];
    const int tid = threadIdx.x;
    const int tx = tid & 15, ty = tid >> 4;
    const int row0 = blockIdx.x * 64;
    const int col0 = blockIdx.y * 64;
    float acc[4][4] = {};
    for (int kb = 0; kb < HID; kb += 16) {
        #pragma unroll
        for (int q = 0; q < 4; ++q) {
            int idx = tid + q * 256;
            int mm = idx >> 4, kk = idx & 15;
            As[kk][mm] = enc[(size_t)(row0 + mm) * HID + kb + kk];
            Bs[kk][mm] = aW[(size_t)(col0 + mm) * HID + kb + kk];
        }
        __syncthreads();
        #pragma unroll
        for (int kk = 0; kk < 16; ++kk) {
            float a[4], b[4];
            #pragma unroll
            for (int i = 0; i < 4; ++i) a[i] = As[kk][ty * 4 + i];
            #pragma unroll
            for (int j = 0; j < 4; ++j) b[j] = Bs[kk][tx * 4 + j];
            #pragma unroll
            for (int i = 0; i < 4; ++i)
                #pragma unroll
                for (int j = 0; j < 4; ++j) acc[i][j] += a[i] * b[j];
        }
        __syncthreads();
    }
    #pragma unroll
    for (int i = 0; i < 4; ++i) {
        float rs = 0.f;
        #pragma unroll
        for (int j = 0; j < 4; ++j) {
            int col = col0 + tx * 4 + j;
            rs += tanhf(acc[i][j] + ab[col]) * aw[col];
        }
        red[ty * 4 + i][tx] = rs;
    }
    __syncthreads();
    if (tid < 64) {
        float v = 0.f;
        #pragma unroll
        for (int x = 0; x < 16; ++x) v += red[tid][x];
        part[(size_t)(row0 + tid) * 8 + blockIdx.y] = v;
    }
}

// ---------------- softmax over t per word ----------------
__global__ void alpha_softmax(const float* __restrict__ part, float* __restrict__ al)
{
    int n = blockIdx.x * blockDim.x + threadIdx.x;   // NW
    float sc[TC];
    #pragma unroll
    for (int t = 0; t < TC; ++t) {
        float v = 0.f;
        #pragma unroll
        for (int q = 0; q < 8; ++q) v += part[(size_t)(t * NW + n) * 8 + q];
        sc[t] = v;
    }
    float m = -1e30f;
    #pragma unroll
    for (int t = 0; t < TC; ++t) m = fmaxf(m, sc[t]);
    float ssum = 0.f;
    #pragma unroll
    for (int t = 0; t < TC; ++t) { sc[t] = expf(sc[t] - m); ssum += sc[t]; }
    float inv = 1.f / ssum;
    #pragma unroll
    for (int t = 0; t < TC; ++t) al[t * NW + n] = sc[t] * inv;
}

// ---------------- context ----------------
__global__ void context_kernel(const float* __restrict__ al, const float* __restrict__ enc,
                               float* __restrict__ ctx)
{
    int id = blockIdx.x * blockDim.x + threadIdx.x;   // NW*HID
    int n = id >> 9, h = id & (HID - 1);
    float v = 0.f;
    #pragma unroll
    for (int t = 0; t < TC; ++t)
        v += al[t * NW + n] * enc[((size_t)t * NW + n) * HID + h];
    ctx[id] = v;
}

// ---------------- word input-projection GEMM ----------------
__global__ __launch_bounds__(256)
void word_proj_gemm(const float* __restrict__ word_emb, const int* __restrict__ word_seq,
                    const float* __restrict__ ctx,
                    const float* __restrict__ Wih_f, const float* __restrict__ b_fp,
                    const float* __restrict__ Wih_b, const float* __restrict__ b_bp,
                    float* __restrict__ Gw)   // [dir][NW][GATES]
{
    const int d = blockIdx.z;
    const float* W = d ? Wih_b : Wih_f;
    const float* bias = d ? b_bp : b_fp;
    __shared__ float As[16][65];
    __shared__ float Bs[16][65];
    const int tid = threadIdx.x;
    const int tx = tid & 15, ty = tid >> 4;
    const int row0 = blockIdx.x * 64;
    const int col0 = blockIdx.y * 64;
    float acc[4][4] = {};
    for (int kb = 0; kb < KW; kb += 16) {
        #pragma unroll
        for (int q = 0; q < 4; ++q) {
            int idx = tid + q * 256;
            int mm = idx >> 4, kk = idx & 15;
            int k = kb + kk;
            int n = row0 + mm;
            float av = 0.f, bv = 0.f;
            if (k < KW) {
                if (k < EW) av = word_emb[(size_t)word_seq[n] * EW + k];
                else        av = ctx[(size_t)n * HID + (k - EW)];
                bv = W[(size_t)(col0 + mm) * KW + k];
            }
            As[kk][mm] = av;
            Bs[kk][mm] = bv;
        }
        __syncthreads();
        #pragma unroll
        for (int kk = 0; kk < 16; ++kk) {
            float a[4], b[4];
            #pragma unroll
            for (int i = 0; i < 4; ++i) a[i] = As[kk][ty * 4 + i];
            #pragma unroll
            for (int j = 0; j < 4; ++j) b[j] = Bs[kk][tx * 4 + j];
            #pragma unroll
            for (int i = 0; i < 4; ++i)
                #pragma unroll
                for (int j = 0; j < 4; ++j) acc[i][j] += a[i] * b[j];
        }
        __syncthreads();
    }
    float* zo = Gw + (size_t)d * NW * GATES;
    #pragma unroll
    for (int i = 0; i < 4; ++i)
        #pragma unroll
        for (int j = 0; j < 4; ++j) {
            int g = col0 + tx * 4 + j;
            zo[(size_t)(row0 + ty * 4 + i) * GATES + g] = acc[i][j] + bias[g];
        }
}

// ---------------- word BiLSTM: one persistent block per direction ----------------
// 512 threads, 1 block/CU (waves_per_eu(2,2) -> 256 VGPR cap, NO spill).
// Thread owns gate rows {tid, 512+tid}; per row 128 h2v fp16 weight pairs:
// pairs 0..95 in VGPRs (192 regs), pairs 96..127 in LDS (uint2-packed, b64 reads).
__global__ __launch_bounds__(512)
__attribute__((amdgpu_waves_per_eu(2, 2)))
void word_lstm_dir(const float* __restrict__ Whh_fw, const float* __restrict__ Whh_bw,
                   const float* __restrict__ Gw,     // [dir][NW][GATES]
                   float* __restrict__ wout)         // [NW][HID]
{
    extern __shared__ float smem[];
    unsigned int* lwA = (unsigned int*)smem;           // 16*1024 u32 (row0 pairs 96..127)
    unsigned int* lwB = lwA + 16 * 1024;               // 16*1024 u32 (row1 pairs 96..127)
    float* zs = smem + 32 * 1024;                      // [1024]
    unsigned int* hpk = (unsigned int*)(zs + GATES);   // [128] packed half2

    const int d = blockIdx.x;
    const int tid = threadIdx.x;
    const float* Whh = d ? Whh_bw : Whh_fw;
    const float* G = Gw + (size_t)d * NW * GATES;

    const float* r0 = Whh + (size_t)tid * H2;
    const float* r1 = Whh + (size_t)(tid + 512) * H2;
    h2v wv0[96], wv1[96];
    #pragma unroll
    for (int p = 0; p < 96; ++p) {
        h2v w; w.x = (_Float16)r0[2*p]; w.y = (_Float16)r0[2*p+1]; wv0[p] = w;
        h2v v; v.x = (_Float16)r1[2*p]; v.y = (_Float16)r1[2*p+1]; wv1[p] = v;
    }
    #pragma unroll
    for (int s = 0; s < 32; ++s) {
        int p = 96 + s;
        int addr = (s >> 1) * 1024 + tid * 2 + (s & 1);
        U32H a; a.h.x = (_Float16)r0[2*p]; a.h.y = (_Float16)r0[2*p+1];
        lwA[addr] = a.u;
        U32H b; b.h.x = (_Float16)r1[2*p]; b.h.y = (_Float16)r1[2*p+1];
        lwB[addr] = b.u;
    }
    if (tid < 128) hpk[tid] = 0u;
    float c0 = 0.f, c1 = 0.f;
    __syncthreads();

    const int woff = d * H2;
    for (int t = 0; t < NW; ++t) {
        const int tt = d ? (NW - 1 - t) : t;
        float g0 = G[(size_t)tt * GATES + tid];
        float g1 = G[(size_t)tt * GATES + 512 + tid];
        float acc0 = 0.f, acc1 = 0.f;
        const uint4* hp4 = (const uint4*)hpk;
        // pairs 0..95 from VGPRs
        #pragma unroll
        for (int q = 0; q < 24; ++q) {
            uint4 hh = hp4[q];
            #pragma unroll
            for (int r = 0; r < 4; ++r) {
                const int p = q * 4 + r;
                U32H hu; hu.u = (&hh.x)[r];
                acc0 = __builtin_amdgcn_fdot2(hu.h, wv0[p], acc0, false);
                acc1 = __builtin_amdgcn_fdot2(hu.h, wv1[p], acc1, false);
            }
        }
        // pairs 96..127 from LDS (uint2 = two adjacent slots per read)
        #pragma unroll
        for (int q = 24; q < 32; ++q) {
            uint4 hh = hp4[q];
            #pragma unroll
            for (int rr = 0; rr < 2; ++rr) {
                const int s = (q - 24) * 4 + rr * 2;     // 0,2,...,30
                const int base = (s >> 1) * 1024 + tid * 2;
                uint2 a = *(const uint2*)&lwA[base];
                uint2 b = *(const uint2*)&lwB[base];
                U32H h0; h0.u = (&hh.x)[rr * 2];
                U32H h1; h1.u = (&hh.x)[rr * 2 + 1];
                U32H wa0; wa0.u = a.x; U32H wa1; wa1.u = a.y;
                U32H wb0; wb0.u = b.x; U32H wb1; wb1.u = b.y;
                acc0 = __builtin_amdgcn_fdot2(h0.h, wa0.h, acc0, false);
                acc0 = __builtin_amdgcn_fdot2(h1.h, wa1.h, acc0, false);
                acc1 = __builtin_amdgcn_fdot2(h0.h, wb0.h, acc1, false);
                acc1 = __builtin_amdgcn_fdot2(h1.h, wb1.h, acc1, false);
            }
        }
        zs[tid] = acc0 + g0;
        zs[512 + tid] = acc1 + g1;
        __syncthreads();
        if (tid < 128) {
            const int u0 = 2 * tid, u1 = u0 + 1;
            float zi0 = zs[u0],       zi1 = zs[u1];
            float zf0 = zs[256 + u0], zf1 = zs[256 + u1];
            float zg0 = zs[512 + u0], zg1 = zs[512 + u1];
            float zo0 = zs[768 + u0], zo1 = zs[768 + u1];
            c0 = sigf(zf0) * c0 + sigf(zi0) * tanhf(zg0);
            float h0 = sigf(zo0) * tanhf(c0);
            c1 = sigf(zf1) * c1 + sigf(zi1) * tanhf(zg1);
            float h1 = sigf(zo1) * tanhf(c1);
            U32H hp; hp.h.x = (_Float16)h0; hp.h.y = (_Float16)h1;
            hpk[tid] = hp.u;
            float2 hv; hv.x = h0; hv.y = h1;
            *(float2*)&wout[(size_t)tt * HID + woff + u0] = hv;
        }
        __syncthreads();
    }
}

// ---------------- output heads ----------------
__global__ __launch_bounds__(64)
void heads_kernel(const float* __restrict__ wout,
                  const float* __restrict__ hpW, const float* __restrict__ hpb,
                  const float* __restrict__ hnW, const float* __restrict__ hnb,
                  float* __restrict__ out)
{
    const int n = blockIdx.x;
    const int tid = threadIdx.x;
    __shared__ float v[HID];
    #pragma unroll
    for (int q = 0; q < 8; ++q) v[tid + q * 64] = wout[(size_t)n * HID + tid + q * 64];
    __syncthreads();
    float sc = 0.f;
    if (tid < NPOS) {
        for (int k = 0; k < HID; ++k) sc += v[k] * hpW[(size_t)tid * HID + k];
        sc += hpb[tid];
    } else {
        int cc = tid - NPOS;
        for (int k = 0; k < HID; ++k) sc += v[k] * hnW[(size_t)cc * HID + k];
        sc += hnb[cc];
    }
    __shared__ float ssc[64];
    __shared__ float lsep, lsen;
    ssc[tid] = sc;
    __syncthreads();
    if (tid == 0) {
        float m = -1e30f;
        for (int i = 0; i < NPOS; ++i) m = fmaxf(m, ssc[i]);
        float su = 0.f;
        for (int i = 0; i < NPOS; ++i) su += expf(ssc[i] - m);
        lsep = m + logf(su);
    }
    if (tid == 32) {
        float m = -1e30f;
        for (int i = NPOS; i < 64; ++i) m = fmaxf(m, ssc[i]);
        float su = 0.f;
        for (int i = NPOS; i < 64; ++i) su += expf(ssc[i] - m);
        lsen = m + logf(su);
    }
    __syncthreads();
    if (tid < NPOS) out[(size_t)n * NPOS + tid] = sc - lsep;
    else            out[(size_t)NW * NPOS + (size_t)n * NNER + (tid - NPOS)] = sc - lsen;
}

// ---------------- host launch ----------------
extern "C" void kernel_launch(void* const* d_in, const int* in_sizes, int n_in,
                              void* d_out, int out_size, void* d_ws, size_t ws_size,
                              hipStream_t stream) {
    const float* char_emb = (const float*)d_in[0];
    const float* word_emb = (const float*)d_in[1];
    const float* cWih_f   = (const float*)d_in[2];
    const float* cWhh_f   = (const float*)d_in[3];
    const float* cb_f     = (const float*)d_in[4];
    const float* cWih_b   = (const float*)d_in[5];
    const float* cWhh_b   = (const float*)d_in[6];
    const float* cb_b     = (const float*)d_in[7];
    const float* wWih_f   = (const float*)d_in[8];
    const float* wWhh_f   = (const float*)d_in[9];
    const float* wb_f     = (const float*)d_in[10];
    const float* wWih_b   = (const float*)d_in[11];
    const float* wWhh_b   = (const float*)d_in[12];
    const float* wb_b     = (const float*)d_in[13];
    const float* aW       = (const float*)d_in[14];
    const float* ab       = (const float*)d_in[15];
    const float* aw       = (const float*)d_in[16];
    const float* hpW      = (const float*)d_in[17];
    const float* hpb      = (const float*)d_in[18];
    const float* hnW      = (const float*)d_in[19];
    const float* hnb      = (const float*)d_in[20];
    const int*   word_seq = (const int*)d_in[21];
    const int*   char_seq = (const int*)d_in[22];
    float* out = (float*)d_out;
    float* ws  = (float*)d_ws;

    const size_t OFF_ENC  = 0;
    const size_t OFF_Z    = OFF_ENC  + (size_t)TC * NW * HID;
    const size_t OFF_CH   = OFF_Z    + (size_t)2 * NW * GATES;
    const size_t OFF_CC   = OFF_CH   + (size_t)4 * NW * H2;
    const size_t OFF_CTX  = OFF_CC   + (size_t)2 * NW * H2;
    const size_t OFF_WOUT = OFF_CTX  + (size_t)NW * HID;
    const size_t OFF_PART = OFF_WOUT + (size_t)NW * HID;
    const size_t OFF_AL   = OFF_PART + (size_t)TC * NW * 8;

    // --- char BiLSTM, 16 steps ---
    dim3 gchar(NW / 64, GATES / 64, 2);
    for (int s = 0; s < TC; ++s) {
        char_gate_gemm<<<gchar, 256, 0, stream>>>(s, char_emb, char_seq,
            cWih_f, cWhh_f, cWih_b, cWhh_b, ws + OFF_CH, ws + OFF_Z);
        char_pointwise<<<(2 * NW * H2) / 256, 256, 0, stream>>>(s, ws + OFF_Z,
            cb_f, cb_b, ws + OFF_CH, ws + OFF_CC, ws + OFF_ENC);
    }

    // --- attention ---
    score_gemm<<<dim3(TC * NW / 64, HID / 64), 256, 0, stream>>>(
        ws + OFF_ENC, aW, ab, aw, ws + OFF_PART);
    alpha_softmax<<<NW / 256, 256, 0, stream>>>(ws + OFF_PART, ws + OFF_AL);
    context_kernel<<<(NW * HID) / 256, 256, 0, stream>>>(ws + OFF_AL, ws + OFF_ENC, ws + OFF_CTX);

    // --- word input projection ---
    word_proj_gemm<<<dim3(NW / 64, GATES / 64, 2), 256, 0, stream>>>(
        word_emb, word_seq, ws + OFF_CTX, wWih_f, wb_f, wWih_b, wb_b, ws + OFF_Z);

    // --- word BiLSTM: 2 independent persistent blocks, 135680 B dynamic LDS each ---
    const int lds_bytes = (32 * 1024 + GATES + 128) * 4;   // 135680
    hipFuncSetAttribute((const void*)word_lstm_dir,
                        hipFuncAttributeMaxDynamicSharedMemorySize, lds_bytes);
    word_lstm_dir<<<2, 512, lds_bytes, stream>>>(wWhh_f, wWhh_b, ws + OFF_Z, ws + OFF_WOUT);

    // --- heads ---
    heads_kernel<<<NW, 64, 0, stream>>>(ws + OFF_WOUT, hpW, hpb, hnW, hnb, out);
}